// Round 1
// baseline (478.672 us; speedup 1.0000x reference)
//
#include <hip/hip_runtime.h>

// Problem constants (from reference): B=1, T=8192, H=400, DEPTH=32.
#define HDIM 400
#define TLEN 8192
#define DEPTH 32
#define SLICE (DEPTH * HDIM)   // 12800 floats per t
#define BLOCK 256

// One block per timestep t.
// Phase 1: compute val[t] = softmax(W x_t + b)[0] * sigmoid(D . x_t)
// Phase 2: stream the (32,400) slice: row 0 = val, rows 1..31 = 0.
__global__ __launch_bounds__(BLOCK) void stack_memory_kernel(
    const float* __restrict__ hs,   // (T, H)
    const float* __restrict__ W,    // (3, H) row-major
    const float* __restrict__ b,    // (3,)
    const float* __restrict__ D,    // (H,)
    float* __restrict__ out)        // (T, DEPTH, H)
{
    const int t = blockIdx.x;
    const float* __restrict__ x = hs + (size_t)t * HDIM;

    float a0 = 0.f, a1 = 0.f, a2 = 0.f, ad = 0.f;
    for (int i = threadIdx.x; i < HDIM; i += BLOCK) {
        float h = x[i];
        a0 += h * W[i];
        a1 += h * W[HDIM + i];
        a2 += h * W[2 * HDIM + i];
        ad += h * D[i];
    }

    // 64-lane wave reduction
    #pragma unroll
    for (int off = 32; off > 0; off >>= 1) {
        a0 += __shfl_down(a0, off);
        a1 += __shfl_down(a1, off);
        a2 += __shfl_down(a2, off);
        ad += __shfl_down(ad, off);
    }

    __shared__ float s0[4], s1[4], s2[4], sd[4];
    __shared__ float sval;
    const int wave = threadIdx.x >> 6;
    const int lane = threadIdx.x & 63;
    if (lane == 0) { s0[wave] = a0; s1[wave] = a1; s2[wave] = a2; sd[wave] = ad; }
    __syncthreads();
    if (threadIdx.x == 0) {
        float l0 = s0[0] + s0[1] + s0[2] + s0[3] + b[0];
        float l1 = s1[0] + s1[1] + s1[2] + s1[3] + b[1];
        float l2 = s2[0] + s2[1] + s2[2] + s2[3] + b[2];
        float dd = sd[0] + sd[1] + sd[2] + sd[3];
        float m  = fmaxf(l0, fmaxf(l1, l2));
        float e0 = __expf(l0 - m);
        float e1 = __expf(l1 - m);
        float e2 = __expf(l2 - m);
        float p0 = e0 / (e0 + e1 + e2);
        float pv = 1.0f / (1.0f + __expf(-dd));
        sval = p0 * pv;
    }
    __syncthreads();

    const float v = sval;
    float4* __restrict__ o = (float4*)(out + (size_t)t * SLICE);
    const float4 vz = make_float4(0.f, 0.f, 0.f, 0.f);
    const float4 vv = make_float4(v, v, v, v);
    // SLICE/4 = 3200 float4 per block; first HDIM/4 = 100 get val, rest zero.
    for (int i = threadIdx.x; i < SLICE / 4; i += BLOCK) {
        o[i] = (i < HDIM / 4) ? vv : vz;
    }
}

extern "C" void kernel_launch(void* const* d_in, const int* in_sizes, int n_in,
                              void* d_out, int out_size, void* d_ws, size_t ws_size,
                              hipStream_t stream) {
    const float* hs = (const float*)d_in[0];  // (1, 8192, 400)
    const float* W  = (const float*)d_in[1];  // (3, 400)
    const float* b  = (const float*)d_in[2];  // (3,)
    const float* D  = (const float*)d_in[3];  // (1, 400)
    float* out = (float*)d_out;               // (1, 8192, 32, 400)

    stack_memory_kernel<<<TLEN, BLOCK, 0, stream>>>(hs, W, b, D, out);
}

// Round 3
// 424.130 us; speedup vs baseline: 1.1286x; 1.1286x over previous
//
#include <hip/hip_runtime.h>

// Problem constants (from reference): B=1, T=8192, H=400, DEPTH=32.
#define HDIM  400
#define TLEN  8192
#define DEPTH 32
#define SLICE (DEPTH * HDIM)        // 12800 floats per t
#define SLICE4 (SLICE / 4)          // 3200 float4 per t
#define ROW4   (HDIM / 4)           // 100 float4 of val per t
#define NF4   ((size_t)TLEN * SLICE4)  // 26,214,400 float4 total
#define BLOCK 256

// Kernel 1: one wave (64 lanes) per timestep t.
//   val[t] = softmax(W x_t + b)[0] * sigmoid(D . x_t)
// Butterfly reduction: ALL lanes end with the full sums (no divergent
// branch, no uninitialized-value broadcast).
__global__ __launch_bounds__(BLOCK) void val_kernel(
    const float* __restrict__ hs,   // (T, H)
    const float* __restrict__ W,    // (3, H)
    const float* __restrict__ b,    // (3,)
    const float* __restrict__ D,    // (H,)
    float* __restrict__ val)        // (T,)
{
    const int wave = threadIdx.x >> 6;
    const int lane = threadIdx.x & 63;
    const int t = blockIdx.x * (BLOCK / 64) + wave;

    const float* __restrict__ x = hs + (size_t)t * HDIM;

    float a0 = 0.f, a1 = 0.f, a2 = 0.f, ad = 0.f;
    for (int i = lane; i < HDIM; i += 64) {
        float h = x[i];
        a0 += h * W[i];
        a1 += h * W[HDIM + i];
        a2 += h * W[2 * HDIM + i];
        ad += h * D[i];
    }

    // XOR butterfly: every lane ends with the total across all 64 lanes.
    #pragma unroll
    for (int off = 32; off > 0; off >>= 1) {
        a0 += __shfl_xor(a0, off);
        a1 += __shfl_xor(a1, off);
        a2 += __shfl_xor(a2, off);
        ad += __shfl_xor(ad, off);
    }

    float l0 = a0 + b[0];
    float l1 = a1 + b[1];
    float l2 = a2 + b[2];
    float m  = fmaxf(l0, fmaxf(l1, l2));
    float e0 = __expf(l0 - m);
    float e1 = __expf(l1 - m);
    float e2 = __expf(l2 - m);
    float p0 = e0 / (e0 + e1 + e2);
    float pv = 1.0f / (1.0f + __expf(-ad));
    float v  = p0 * pv;

    if (lane == 0) val[t] = v;
}

// Kernel 2: pure grid-stride float4 fill (mimics __amd_rocclr_fillBufferAligned,
// which achieves 6.1 TB/s on this exact buffer). Each output float4 g maps to
// t = g / 3200, w = g % 3200; value = val[t] if w < 100 else 0. The val load
// is only issued by waves overlapping the first 100 float4 of a slice (~4%).
__global__ __launch_bounds__(BLOCK) void fill_kernel(
    const float* __restrict__ val,  // (T,)
    float4* __restrict__ out)       // NF4 float4
{
    const unsigned stride = gridDim.x * BLOCK;
    for (unsigned g = blockIdx.x * BLOCK + threadIdx.x; g < NF4; g += stride) {
        unsigned t = g / SLICE4;            // constant divide -> umulhi
        unsigned w = g - t * SLICE4;
        float v = 0.f;
        if (w < ROW4) v = val[t];
        out[g] = make_float4(v, v, v, v);
    }
}

extern "C" void kernel_launch(void* const* d_in, const int* in_sizes, int n_in,
                              void* d_out, int out_size, void* d_ws, size_t ws_size,
                              hipStream_t stream) {
    const float* hs = (const float*)d_in[0];  // (1, 8192, 400)
    const float* W  = (const float*)d_in[1];  // (3, 400)
    const float* b  = (const float*)d_in[2];  // (3,)
    const float* D  = (const float*)d_in[3];  // (1, 400)
    float* out = (float*)d_out;               // (1, 8192, 32, 400)
    float* val = (float*)d_ws;                // 8192 floats of scratch

    val_kernel<<<TLEN / (BLOCK / 64), BLOCK, 0, stream>>>(hs, W, b, D, val);
    fill_kernel<<<4096, BLOCK, 0, stream>>>(val, (float4*)out);
}